// Round 1
// baseline (294.893 us; speedup 1.0000x reference)
//
#include <hip/hip_runtime.h>

namespace {

typedef __attribute__((ext_vector_type(8))) short short8;   // MFMA A/B frag (8 bf16)
typedef __attribute__((ext_vector_type(4))) float floatx4;  // MFMA C/D frag

constexpr int T    = 512;
constexpr int H    = 64;
constexpr int TPB  = 256;   // 4 waves = 1/SIMD per block
constexpr int MB   = 4;     // grid 512 -> 2 de-phased blocks per CU
constexpr int HST  = 128;   // ushorts per bat row, EXACT (rotation-swizzled, no pad)
constexpr int XSTR = 516;   // xs row stride (floats)
constexpr int FSTR = 68;    // hf32 row stride (floats, head only)

constexpr int DPP_ROR8 = 0x128;  // row_ror:8 -> lane i reads lane i^8 (within row of 16)

__device__ __forceinline__ ushort f2bf(float x) {  // fp32 -> bf16 RN-even (finite)
  unsigned u = __float_as_uint(x);
  unsigned r = u + 0x7fffu + ((u >> 16) & 1u);
  return (ushort)(r >> 16);
}
__device__ __forceinline__ float bf2f(ushort h) {
  return __uint_as_float(((unsigned)h) << 16);
}
__device__ __forceinline__ float fsig(float x) {
  return __builtin_amdgcn_rcpf(1.0f + __expf(-x));
}
__device__ __forceinline__ float ftanh(float x) {
  return fmaf(-2.0f, __builtin_amdgcn_rcpf(1.0f + __expf(2.0f * x)), 1.0f);
}
__device__ __forceinline__ float swz8(float v) {   // value from lane^8 (row of 16), VALU pipe
  return __int_as_float(__builtin_amdgcn_update_dpp(
      0, __float_as_int(v), DPP_ROR8, 0xf, 0xf, true));
}

// R24: de-phased dual-workgroup topology.
// R23/R19 measured ~1010 cyc/step = ~600 issue/SIMD + ~330 IN-PHASE chain
// stall: the per-step barrier re-syncs all waves of the block, so both
// waves/SIMD stall on the identical ds_read->MFMA->exp chain simultaneously.
// Fix: MB=4, TPB=256, grid=512 -> 2 INDEPENDENT blocks per CU. Their
// barriers are per-workgroup, so the blocks drift out of phase and one
// block's issue fills the other's dependency stalls.
// Column relabel to keep 16 MFMA cols full with 4 batches:
//   col n = bat(n&3) | dup(bit2) | type(bit3).  Lanes n and n^4 read the
// same h bytes (LDS broadcast). The hi/lo combine is now SYMMETRIC:
//   sum_t = acc_t + swz8(acc_t)   (lane^8 flips only the type bit)
// so the type bit is freed post-combine and (bit3,bit2) = n>>2 selects the
// lane's OWN tile among the wave's 4 tiles. Each lane owns one (unit,bat):
// per-SIMD gate/trans/LDS issue is unchanged vs R23; only MFMA issue rises
// (16/wave vs 8, same 16-col instr now carrying 4 bats), ~+100 cyc/SIMD/step
// against the ~330 cyc stall this recovers.
// Precision scheme (split-bf16 W and h, trunc split, rot-swizzled LDS rows)
// carried over verbatim from R19/R23 (absmax 3e-5 verified there).
__global__ __launch_bounds__(TPB, 2)
void lstm_mfma(const float* __restrict__ xg,
               const float* __restrict__ W_ih,
               const float* __restrict__ W_hh,
               const float* __restrict__ b_ih,
               const float* __restrict__ b_hh,
               const float* __restrict__ fc1_w,
               const float* __restrict__ fc1_b,
               const float* __restrict__ fc2_w,
               const float* __restrict__ fc2_b,
               float* __restrict__ out)
{
  __shared__ __align__(16) ushort hA[MB * HST];   // h double-buffer (rot-swizzled rows)
  __shared__ __align__(16) ushort hB[MB * HST];
  __shared__ __align__(16) float  xs[MB * XSTR];
  __shared__ __align__(16) float  hf[MB * FSTR];  // final h fp32 (head; written once)
  __shared__ float zs[MB][16];

  const int tid  = threadIdx.x;
  const int b0   = blockIdx.x * MB;
  const int lane = tid & 63;
  const int wj   = tid >> 6;       // wave 0..3 -> tiles {4wj..4wj+3}
  const int n    = lane & 15;      // MFMA col: bat n&3 | dup bit2 | type bit3
  const int kg   = lane >> 4;      // k-group (A/B), row-quad (D)
  const int bat  = n & 3;
  const int c2   = (n >> 2) & 1;   // dup bit -> low tile-select bit
  const int ty   = n >> 3;         // type bit (hi/lo col) -> high tile-select bit
  const int rot  = 24 * bat;       // per-bat rotation (ushorts; mult of 8 -> 16B-aligned)

  // ---- stage x (coalesced float4) ----
  for (int i = tid; i < MB * T / 4; i += TPB) {
    const int xb = i >> 7, tq = i & 127;
    float4 v = ((const float4*)(xg + (size_t)(b0 + xb) * T))[tq];
    *(float4*)&xs[xb * XSTR + tq * 4] = v;
  }
  // ---- zero h buffers (h0 = 0) ----
  for (int i = tid; i < MB * HST; i += TPB) { hA[i] = 0; hB[i] = 0; }

  // ---- A-frags for tiles 4wj..4wj+3 (gate-interleaved permutation, R12-verified) ----
  short8 whi[4][2], wlo[4][2];     // [tile][k-half]
#pragma unroll
  for (int tt = 0; tt < 4; ++tt) {
    const int r    = 4 * wj + tt;
    const int arow = 64 * (n & 3) + 4 * r + (n >> 2);   // gate n&3, local unit n>>2
    const float* wr = W_hh + arow * H + 8 * kg;
    const float4 p0 = *(const float4*)(wr + 0);
    const float4 p1 = *(const float4*)(wr + 4);
    const float4 p2 = *(const float4*)(wr + 32);
    const float4 p3 = *(const float4*)(wr + 36);
    const float v0[8] = {p0.x, p0.y, p0.z, p0.w, p1.x, p1.y, p1.z, p1.w};
    const float v1[8] = {p2.x, p2.y, p2.z, p2.w, p3.x, p3.y, p3.z, p3.w};
#pragma unroll
    for (int j = 0; j < 8; ++j) {
      const ushort h0 = f2bf(v0[j]);
      whi[tt][0][j] = (short)h0;
      wlo[tt][0][j] = (short)f2bf(v0[j] - bf2f(h0));   // exact remainder, then RN
      const ushort h1 = f2bf(v1[j]);
      whi[tt][1][j] = (short)h1;
      wlo[tt][1][j] = (short)f2bf(v1[j] - bf2f(h1));
    }
  }

  // ---- owned c-state: unit u = 16wj + 4*(n>>2) + kg, batch bat ----
  const int u = 16 * wj + 4 * (n >> 2) + kg;
  float bia[4], wih[4];
#pragma unroll
  for (int j = 0; j < 4; ++j) {                 // gate rows: i,f,g,o = 64j + u
    const int row = 64 * j + u;
    bia[j] = b_ih[row] + b_hh[row];
    wih[j] = W_ih[row];
  }

  // ---- swizzled LDS offsets (precomputed; rotation wrap => separate mods) ----
  const int Lrd   = 64 * ty + 8 * kg;                       // logical read base
  const int rd0   = bat * HST + ((Lrd      + rot) & 127);   // f0 (k 0..31 of my type)
  const int rd1   = bat * HST + ((Lrd + 32 + rot) & 127);   // f1 (k 32..63)
  const int whi_o = bat * HST + ((u        + rot) & 127);   // h hi write
  const int wlo_o = bat * HST + ((u + 64   + rot) & 127);   // h lo write
  const float* xq = &xs[bat * XSTR];
  float c = 0.0f, hk = 0.0f;

  __syncthreads();

#define STEP(HR, HW, XT)                                                       \
  {                                                                            \
    const short8 f0 = *(const short8*)((HR) + rd0);                            \
    const short8 f1 = *(const short8*)((HR) + rd1);                            \
    const floatx4 zf = {0.f, 0.f, 0.f, 0.f};                                   \
    /* 4 independent 4-deep chains (tiles 4wj..4wj+3); HW interleaves them */  \
    floatx4 a0 = __builtin_amdgcn_mfma_f32_16x16x32_bf16(whi[0][0], f0, zf, 0, 0, 0); \
    floatx4 a1 = __builtin_amdgcn_mfma_f32_16x16x32_bf16(whi[1][0], f0, zf, 0, 0, 0); \
    floatx4 a2 = __builtin_amdgcn_mfma_f32_16x16x32_bf16(whi[2][0], f0, zf, 0, 0, 0); \
    floatx4 a3 = __builtin_amdgcn_mfma_f32_16x16x32_bf16(whi[3][0], f0, zf, 0, 0, 0); \
    a0 = __builtin_amdgcn_mfma_f32_16x16x32_bf16(wlo[0][0], f0, a0, 0, 0, 0);  \
    a1 = __builtin_amdgcn_mfma_f32_16x16x32_bf16(wlo[1][0], f0, a1, 0, 0, 0);  \
    a2 = __builtin_amdgcn_mfma_f32_16x16x32_bf16(wlo[2][0], f0, a2, 0, 0, 0);  \
    a3 = __builtin_amdgcn_mfma_f32_16x16x32_bf16(wlo[3][0], f0, a3, 0, 0, 0);  \
    a0 = __builtin_amdgcn_mfma_f32_16x16x32_bf16(whi[0][1], f1, a0, 0, 0, 0);  \
    a1 = __builtin_amdgcn_mfma_f32_16x16x32_bf16(whi[1][1], f1, a1, 0, 0, 0);  \
    a2 = __builtin_amdgcn_mfma_f32_16x16x32_bf16(whi[2][1], f1, a2, 0, 0, 0);  \
    a3 = __builtin_amdgcn_mfma_f32_16x16x32_bf16(whi[3][1], f1, a3, 0, 0, 0);  \
    a0 = __builtin_amdgcn_mfma_f32_16x16x32_bf16(wlo[0][1], f1, a0, 0, 0, 0);  \
    a1 = __builtin_amdgcn_mfma_f32_16x16x32_bf16(wlo[1][1], f1, a1, 0, 0, 0);  \
    a2 = __builtin_amdgcn_mfma_f32_16x16x32_bf16(wlo[2][1], f1, a2, 0, 0, 0);  \
    a3 = __builtin_amdgcn_mfma_f32_16x16x32_bf16(wlo[3][1], f1, a3, 0, 0, 0);  \
    float p[4];                                                                \
    _Pragma("unroll") for (int j = 0; j < 4; ++j) {                            \
      /* symmetric hi/lo combine: lane^8 flips ONLY the type bit, so      */   \
      /* partner's c2-select picks the SAME tile-pair member.             */   \
      const float m  = c2 ? a1[j] : a0[j];                                     \
      const float q  = c2 ? a3[j] : a2[j];                                     \
      const float sm = m + swz8(m);   /* full sum of tile (0|c2) */            \
      const float sq = q + swz8(q);   /* full sum of tile (2|c2) */            \
      const float own = ty ? sq : sm; /* my tile t = n>>2 */                   \
      p[j] = own + fmaf((XT), wih[j], bia[j]);                                 \
    }                                                                          \
    const float ig = fsig(p[0]);                                               \
    const float fg = fsig(p[1]);                                               \
    const float gc = ftanh(p[2]);                                              \
    const float og = fsig(p[3]);                                               \
    c  = fmaf(fg, c, ig * gc);                                                 \
    hk = og * ftanh(c);                                                        \
    /* trunc split both halves (R19): hi = trunc(hk), lo = trunc(hk-hi) */     \
    const ushort hib = (ushort)(__float_as_uint(hk) >> 16);                    \
    const float  rem = hk - bf2f(hib);                                         \
    (HW)[whi_o] = hib;                                                         \
    (HW)[wlo_o] = (ushort)(__float_as_uint(rem) >> 16);                        \
    __syncthreads();                                                           \
  }

  for (int t = 0; t < T; t += 2) {
    const float2 x2 = *(const float2*)(xq + t);   // one b64 read feeds both steps
    STEP(hA, hB, x2.x);
    STEP(hB, hA, x2.y);
  }
#undef STEP

  // ---- final h (fp32, from registers) -> LDS once; then the head ----
  hf[bat * FSTR + u] = hk;
  __syncthreads();
  if (tid < MB * 16) {
    const int bq = tid >> 4, j2 = tid & 15;   // 4 batches x 16 hidden2
    float s = fc1_b[j2];
    const float* fw = fc1_w + j2 * H;
#pragma unroll
    for (int k = 0; k < H; ++k) s = fmaf(hf[bq * FSTR + k], fw[k], s);
    s = fmaxf(s, 0.0f);
    zs[bq][j2] = s * fc2_w[j2];
  }
  __syncthreads();
  if (tid < MB) {
    float s = fc2_b[0];
#pragma unroll
    for (int j = 0; j < 16; ++j) s += zs[tid][j];
    out[b0 + tid] = s;
  }
}

}  // namespace

extern "C" void kernel_launch(void* const* d_in, const int* in_sizes, int n_in,
                              void* d_out, int out_size, void* d_ws, size_t ws_size,
                              hipStream_t stream) {
  const float* xg    = (const float*)d_in[0];
  const float* W_ih  = (const float*)d_in[1];
  const float* W_hh  = (const float*)d_in[2];
  const float* b_ih  = (const float*)d_in[3];
  const float* b_hh  = (const float*)d_in[4];
  const float* fc1_w = (const float*)d_in[5];
  const float* fc1_b = (const float*)d_in[6];
  const float* fc2_w = (const float*)d_in[7];
  const float* fc2_b = (const float*)d_in[8];
  float* out = (float*)d_out;

  dim3 grid(2048 / MB);   // 512 blocks -> 2 de-phased workgroups per CU
  dim3 block(TPB);
  hipLaunchKernelGGL(lstm_mfma, grid, block, 0, stream,
                     xg, W_ih, W_hh, b_ih, b_hh, fc1_w, fc1_b, fc2_w, fc2_b, out);
}